// Round 9
// baseline (994.972 us; speedup 1.0000x reference)
//
#include <hip/hip_runtime.h>
#include <hip/hip_bf16.h>

// ---------------------------------------------------------------------------
// WeightOnlyLinear: y = x @ dequant4(qweight, scales, qzeros) + bias
//   x (8192,4096) fp32 | scales (32,12288) | bias (12288) | qweight (512,12288)
//   qzeros (32,1536) | out (8192,12288) fp32
// R9: R8 (32x32x16 MFMA, ring-4 K-half slots, x4-unrolled phases, vmcnt(8) +
//     1 barrier per phase) with FRAGMENT-MAJOR LDS: each 1KB MFMA operand
//     stored lane-linear (lane*16). ds_read_b128 contiguous -> 0 conflicts,
//     no address math; global_load_lds dest linear, per-lane global source
//     carries the permutation (rule 21).
// ---------------------------------------------------------------------------

typedef __attribute__((ext_vector_type(8))) short short8;
typedef __attribute__((ext_vector_type(4))) float f32x4;
typedef __attribute__((ext_vector_type(16))) float f32x16;

__device__ __forceinline__ short f2bf(float f) {
  unsigned u = __float_as_uint(f);
  u += 0x7fffu + ((u >> 16) & 1u);
  return (short)(u >> 16);
}

__device__ __forceinline__ void gload_lds16(const void* g, void* l) {
  __builtin_amdgcn_global_load_lds(
      (const __attribute__((address_space(1))) void*)g,
      (__attribute__((address_space(3))) void*)l,
      16, 0, 0);
}

__device__ __forceinline__ void bar() {
  asm volatile("" ::: "memory");
  __builtin_amdgcn_s_barrier();
  asm volatile("" ::: "memory");
}
__device__ __forceinline__ void wait_vm8() {
  asm volatile("s_waitcnt vmcnt(8)" ::: "memory");
}
__device__ __forceinline__ void wait_vm4() {
  asm volatile("s_waitcnt vmcnt(4)" ::: "memory");
}
__device__ __forceinline__ void wait_vm0() {
  asm volatile("s_waitcnt vmcnt(0)" ::: "memory");
}

// ---------------------------------------------------------------------------
// Pass 1: dequant + transpose. qweight (K/8, N) int32 -> Wt (N, K) bf16.
// ---------------------------------------------------------------------------
__global__ __launch_bounds__(256) void dequant_kernel(
    const int* __restrict__ qweight, const int* __restrict__ qzeros,
    const float* __restrict__ scales, short* __restrict__ Wt,
    int in_f, int out_f) {
  __shared__ __align__(16) short T[64][72];
  const int n0 = blockIdx.x * 64;
  const int k0 = blockIdx.y * 64;
  const int t = threadIdx.x;
  const int nl = t & 63;
  const int kw = t >> 6;
  const int n = n0 + nl;
  const int g = k0 >> 7;
  const float sc = scales[(size_t)g * out_f + n];
  const int zpw = qzeros[(size_t)g * (out_f >> 3) + (n >> 3)];
  const float zp = (float)(((zpw >> ((n & 7) * 4)) & 15) + 1);
  const float zs = zp * sc;
#pragma unroll
  for (int rr = 0; rr < 2; ++rr) {
    const int kwi = kw + rr * 4;
    const int w = qweight[(size_t)((k0 >> 3) + kwi) * out_f + n];
    short8 v;
#pragma unroll
    for (int e = 0; e < 8; ++e) {
      float f = (float)((w >> (4 * e)) & 15) * sc - zs;
      v[e] = f2bf(f);
    }
    *(short8*)&T[nl][kwi * 8] = v;
  }
  __syncthreads();
#pragma unroll
  for (int rr = 0; rr < 2; ++rr) {
    const int c = rr * 256 + t;
    const int row = c >> 3, ch = c & 7;
    *(short8*)&Wt[(size_t)(n0 + row) * in_f + k0 + ch * 8] =
        *(const short8*)&T[row][ch * 8];
  }
}

// ---------------------------------------------------------------------------
// Pass 2: x fp32 -> bf16.
// ---------------------------------------------------------------------------
__global__ __launch_bounds__(256) void cvt_kernel(
    const float* __restrict__ x, short* __restrict__ xb, long n8) {
  long i = (long)blockIdx.x * blockDim.x + threadIdx.x;
  if (i >= n8) return;
  const float* src = x + i * 8;
  float4 a = *(const float4*)src;
  float4 b = *(const float4*)(src + 4);
  short8 v;
  v[0] = f2bf(a.x); v[1] = f2bf(a.y); v[2] = f2bf(a.z); v[3] = f2bf(a.w);
  v[4] = f2bf(b.x); v[5] = f2bf(b.y); v[6] = f2bf(b.z); v[7] = f2bf(b.w);
  *(short8*)(xb + i * 8) = v;
}

// ---------------------------------------------------------------------------
// Pass 3 (R9): 256x256 GEMM, 512 threads = 8 waves (2M x 4N), wave 128x64.
// MFMA 32x32x16 bf16; wave tile 4x2 frags of 32x32.
// LDS ring: 4 slots x 32KB, FRAGMENT-MAJOR:
//   A region (16KB @0):    chunk c = rb*128 + kh*64 + lane  (rb=row-block/32,
//     kh=k-16-half, lane=(row&31)+32*(k>=8));  byte addr = c*16.
//   B region (16KB @16384): same with cb = col-block/32.
// Reads: ds_read_b128 at (region + rb*2048 + kh*1024 + lane*16) -> contiguous
// 1KB per wave per operand = minimal banking, all offsets immediate.
// Staging: thread stages chunks {tid, tid+512} of A and of B (4 gloads);
// global src per chunk: row = (c>>7)*32 + (c&31), kc8 = (c>>5)&3.
// Ledger identical to R4/R8: vmcnt(8)+bar per phase; tail 8/8/4/0.
// ---------------------------------------------------------------------------
#define GBM 256
#define GBN 256

__global__ __launch_bounds__(512, 2) void gemm256_kernel(
    const short* __restrict__ A, const short* __restrict__ Bt,
    const float* __restrict__ bias, float* __restrict__ C,
    int M, int N, int K) {
  __shared__ __align__(16) char lds[4][32768];
  const int tid = threadIdx.x;
  const int nbx = N / GBN;
  const int nwg = gridDim.x;
  int bid = blockIdx.x;
  if ((nwg & 7) == 0) bid = (bid & 7) * (nwg >> 3) + (bid >> 3);  // T1
  const int bm = (bid / nbx) * GBM;
  const int bn = (bid % nbx) * GBN;

  const int wid = tid >> 6, lane = tid & 63;
  const int wr = wid >> 2, wc = wid & 3;  // 2x4 wave grid
  const int l31 = lane & 31;
  const int lq2 = lane >> 5;

  const int P = K >> 5;  // K-halves; P % 4 == 0, P >= 8

  char* lb = &lds[0][0];

  // --- ds_read base pointers [hi = slot>>1]; (slot&1)*32768 + rb*2048 +
  //     kh*1024 are immediates (max 32768+6144+1024+15*... < 65536).
  const char* aB[2];
  const char* bB[2];
  aB[0] = lb + wr * 8192 + lane * 16;            // rb = wr*4 + i
  aB[1] = aB[0] + 65536;
  bB[0] = lb + 16384 + wc * 4096 + lane * 16;    // cb = wc*2 + j
  bB[1] = bB[0] + 65536;

  // --- stage addressing: chunks c in {tid, tid+512} for A and for B.
  // chunk c: row = (c>>7)*32 + (c&31); kc8 = (c>>5)&3 (8-element k group).
  // c and c+512 share low 7 bits -> row(+128), same kc8.
  const int row0 = ((tid >> 7) << 5) + (tid & 31);
  const int kc0 = (tid >> 5) & 3;
  const short* pA0 = A + (size_t)(bm + row0) * K + kc0 * 8;
  const short* pA1 = pA0 + (size_t)128 * K;
  const short* pB0 = Bt + (size_t)(bn + row0) * K + kc0 * 8;
  const short* pB1 = pB0 + (size_t)128 * K;
  char* dstA0 = lb + tid * 16;
  char* dstA1 = dstA0 + 8192;
  char* dstB0 = dstA0 + 16384;
  char* dstB1 = dstA0 + 24576;

#define STAGE(NSL, KOF)                              \
  do {                                               \
    gload_lds16(pA0 + (KOF), dstA0 + (NSL) * 32768); \
    gload_lds16(pA1 + (KOF), dstA1 + (NSL) * 32768); \
    gload_lds16(pB0 + (KOF), dstB0 + (NSL) * 32768); \
    gload_lds16(pB1 + (KOF), dstB1 + (NSL) * 32768); \
  } while (0)

  f32x16 acc[4][2] = {};

#define PHASE(SL, ST)                                                         \
  do {                                                                        \
    short8 a0[4], a1[4], b0[2], b1[2];                                        \
    _Pragma("unroll") for (int i = 0; i < 4; ++i) a0[i] =                     \
        *(const short8*)(aB[(SL) >> 1] + ((SL)&1) * 32768 + i * 2048);        \
    _Pragma("unroll") for (int j = 0; j < 2; ++j) b0[j] =                     \
        *(const short8*)(bB[(SL) >> 1] + ((SL)&1) * 32768 + j * 2048);        \
    _Pragma("unroll") for (int i = 0; i < 4; ++i) a1[i] =                     \
        *(const short8*)(aB[(SL) >> 1] + ((SL)&1) * 32768 + i * 2048 + 1024); \
    _Pragma("unroll") for (int j = 0; j < 2; ++j) b1[j] =                     \
        *(const short8*)(bB[(SL) >> 1] + ((SL)&1) * 32768 + j * 2048 + 1024); \
    if (ST) STAGE(((SL) + 3) & 3, ((SL) + 3) * 32);                           \
    __builtin_amdgcn_s_setprio(1);                                            \
    _Pragma("unroll") for (int i = 0; i < 4; ++i)                             \
        _Pragma("unroll") for (int j = 0; j < 2; ++j) acc[i][j] =             \
            __builtin_amdgcn_mfma_f32_32x32x16_bf16(a0[i], b0[j], acc[i][j],  \
                                                    0, 0, 0);                 \
    _Pragma("unroll") for (int i = 0; i < 4; ++i)                             \
        _Pragma("unroll") for (int j = 0; j < 2; ++j) acc[i][j] =             \
            __builtin_amdgcn_mfma_f32_32x32x16_bf16(a1[i], b1[j], acc[i][j],  \
                                                    0, 0, 0);                 \
    __builtin_amdgcn_s_setprio(0);                                            \
  } while (0)

  // --- prologue: stage K-halves 0,1,2 into slots 0,1,2 (12 loads) ---
  STAGE(0, 0);
  STAGE(1, 32);
  STAGE(2, 64);

  // --- main loop: P/4-1 iterations of 4 phases, all staging ---
  const int nIt = P / 4 - 1;
  for (int it = 0; it < nIt; ++it) {
    wait_vm8(); bar(); PHASE(0, true);
    wait_vm8(); bar(); PHASE(1, true);
    wait_vm8(); bar(); PHASE(2, true);
    wait_vm8(); bar(); PHASE(3, true);
    pA0 += 128; pA1 += 128; pB0 += 128; pB1 += 128;
  }
  // --- tail: phase P-4 stages K-half P-1; drain 8/8/4/0 ---
  wait_vm8(); bar(); PHASE(0, true);
  wait_vm8(); bar(); PHASE(1, false);
  wait_vm4(); bar(); PHASE(2, false);
  wait_vm0(); bar(); PHASE(3, false);

#undef PHASE
#undef STAGE

  // --- epilogue: C = acc + bias.
  // 32x32 C/D map: col = lane&31, row = (reg&3) + 8*(reg>>2) + 4*(lane>>5)
  const int crow0 = bm + wr * 128 + 4 * lq2;
#pragma unroll
  for (int j = 0; j < 2; ++j) {
    const int ccol = bn + wc * 64 + j * 32 + l31;
    const float bv = bias[ccol];
#pragma unroll
    for (int i = 0; i < 4; ++i) {
#pragma unroll
      for (int reg = 0; reg < 16; ++reg) {
        const int row = crow0 + i * 32 + (reg & 3) + 8 * (reg >> 2);
        C[(size_t)row * N + ccol] = acc[i][j][reg] + bv;
      }
    }
  }
}

// ---------------------------------------------------------------------------
// 128x128x64 GEMM (fallback for non-256-divisible shapes).
// ---------------------------------------------------------------------------
#define BM 128
#define BN 128
#define BK 64

template <bool A_BF16>
__global__ __launch_bounds__(256) void gemm_bias_kernel(
    const void* __restrict__ Av, const short* __restrict__ Bt,
    const float* __restrict__ bias, float* __restrict__ C,
    int M, int N, int K) {
  __shared__ __align__(16) short As[BM * BK];
  __shared__ __align__(16) short Bs[BN * BK];
  const int tid = threadIdx.x;
  const int bm = blockIdx.y * BM;
  const int bn = blockIdx.x * BN;
  const int wid = tid >> 6, lane = tid & 63;
  const int wr = wid >> 1, wc = wid & 1;
  const int lrow = lane & 15;
  const int lk = (lane >> 4) * 8;

  f32x4 acc[4][4] = {};

  for (int kt = 0; kt < K; kt += BK) {
    if constexpr (A_BF16) {
      const short* A = (const short*)Av;
#pragma unroll
      for (int r = 0; r < 4; ++r) {
        const int c = r * 256 + tid;
        const int row = c >> 3, ch = c & 7;
        gload_lds16(A + (size_t)(bm + row) * K + kt + ch * 8,
                    (char*)As + c * 16);
      }
    } else {
      const float* A = (const float*)Av;
#pragma unroll
      for (int r = 0; r < 4; ++r) {
        const int c = r * 256 + tid;
        const int row = c >> 3, ch = c & 7;
        const float* src = A + (size_t)(bm + row) * K + kt + ch * 8;
        float4 f0 = *(const float4*)src;
        float4 f1 = *(const float4*)(src + 4);
        short8 v;
        v[0] = f2bf(f0.x); v[1] = f2bf(f0.y); v[2] = f2bf(f0.z); v[3] = f2bf(f0.w);
        v[4] = f2bf(f1.x); v[5] = f2bf(f1.y); v[6] = f2bf(f1.z); v[7] = f2bf(f1.w);
        *(short8*)((char*)As + c * 16) = v;
      }
    }
#pragma unroll
    for (int r = 0; r < 4; ++r) {
      const int c = r * 256 + tid;
      const int row = c >> 3, ch = c & 7;
      gload_lds16(Bt + (size_t)(bn + row) * K + kt + ch * 8,
                  (char*)Bs + c * 16);
    }
    __syncthreads();
#pragma unroll
    for (int kk = 0; kk < 2; ++kk) {
      short8 af[4], bf[4];
#pragma unroll
      for (int i = 0; i < 4; ++i)
        af[i] = *(const short8*)&As[(wr * 64 + i * 16 + lrow) * BK + kk * 32 + lk];
#pragma unroll
      for (int j = 0; j < 4; ++j)
        bf[j] = *(const short8*)&Bs[(wc * 64 + j * 16 + lrow) * BK + kk * 32 + lk];
#pragma unroll
      for (int i = 0; i < 4; ++i)
#pragma unroll
        for (int j = 0; j < 4; ++j)
          acc[i][j] = __builtin_amdgcn_mfma_f32_16x16x32_bf16(
              af[i], bf[j], acc[i][j], 0, 0, 0);
    }
    __syncthreads();
  }

  const int crow0 = bm + wr * 64 + (lane >> 4) * 4;
  const int ccol0 = bn + wc * 64 + (lane & 15);
#pragma unroll
  for (int j = 0; j < 4; ++j) {
    const float bv = bias[ccol0 + j * 16];
#pragma unroll
    for (int i = 0; i < 4; ++i) {
#pragma unroll
      for (int r = 0; r < 4; ++r) {
        C[(size_t)(crow0 + i * 16 + r) * N + ccol0 + j * 16] = acc[i][j][r] + bv;
      }
    }
  }
}

// ---------------------------------------------------------------------------
// Last-resort fallback: naive fused dequant GEMM.
// ---------------------------------------------------------------------------
__global__ __launch_bounds__(256) void naive_kernel(
    const float* __restrict__ x, const float* __restrict__ scales,
    const float* __restrict__ bias, const int* __restrict__ qw,
    const int* __restrict__ qz, float* __restrict__ out,
    int M, int K, int N) {
  long idx = (long)blockIdx.x * blockDim.x + threadIdx.x;
  if (idx >= (long)M * N) return;
  const int n = (int)(idx % N);
  const int m = (int)(idx / N);
  float acc = 0.f;
  for (int g = 0; g < K / 128; ++g) {
    const float sc = scales[(size_t)g * N + n];
    const float zp =
        (float)(((qz[(size_t)g * (N >> 3) + (n >> 3)] >> ((n & 7) * 4)) & 15) + 1);
    const float zs = zp * sc;
    for (int kw = 0; kw < 16; ++kw) {
      const int w = qw[(size_t)(g * 16 + kw) * N + n];
      const float* xp = &x[(size_t)m * K + g * 128 + kw * 8];
#pragma unroll
      for (int e = 0; e < 8; ++e)
        acc += xp[e] * ((float)((w >> (4 * e)) & 15) * sc - zs);
    }
  }
  out[idx] = acc + bias[n];
}

// ---------------------------------------------------------------------------
extern "C" void kernel_launch(void* const* d_in, const int* in_sizes, int n_in,
                              void* d_out, int out_size, void* d_ws,
                              size_t ws_size, hipStream_t stream) {
  const float* x = (const float*)d_in[0];
  const float* scales = (const float*)d_in[1];
  const float* bias = (const float*)d_in[2];
  const int* qweight = (const int*)d_in[3];
  const int* qzeros = (const int*)d_in[4];
  float* out = (float*)d_out;

  const int out_f = in_sizes[2];            // 12288
  const int kwords = in_sizes[3] / out_f;   // 512
  const int in_f = kwords * 8;              // 4096
  const int tokens = in_sizes[0] / in_f;    // 8192
  const int M = tokens, K = in_f, N = out_f;

  const size_t wt_bytes = (size_t)K * N * sizeof(short);
  const size_t xb_bytes = (size_t)M * K * sizeof(short);

  const bool div128 = (M % BM == 0) && (N % BN == 0) && (K % BK == 0) &&
                      (K % 128 == 0) && (N % 64 == 0);
  const bool div256 = (M % GBM == 0) && (N % GBN == 0) && (K % 256 == 0);

  if (div128 && ws_size >= wt_bytes + xb_bytes) {
    short* Wt = (short*)d_ws;
    short* xb = (short*)((char*)d_ws + wt_bytes);
    dequant_kernel<<<dim3(N / 64, K / 64), 256, 0, stream>>>(
        qweight, qzeros, scales, Wt, K, N);
    const long n8 = (long)M * K / 8;
    cvt_kernel<<<(int)((n8 + 255) / 256), 256, 0, stream>>>(x, xb, n8);
    if (div256) {
      gemm256_kernel<<<(M / GBM) * (N / GBN), 512, 0, stream>>>(
          xb, Wt, bias, out, M, N, K);
    } else {
      gemm_bias_kernel<true><<<dim3(N / BN, M / BM), 256, 0, stream>>>(
          xb, Wt, bias, out, M, N, K);
    }
  } else if (div128 && ws_size >= wt_bytes) {
    short* Wt = (short*)d_ws;
    dequant_kernel<<<dim3(N / 64, K / 64), 256, 0, stream>>>(
        qweight, qzeros, scales, Wt, K, N);
    gemm_bias_kernel<false><<<dim3(N / BN, M / BM), 256, 0, stream>>>(
        x, Wt, bias, out, M, N, K);
  } else {
    const long total = (long)M * N;
    naive_kernel<<<(int)((total + 255) / 256), 256, 0, stream>>>(
        x, scales, bias, qweight, qzeros, out, M, K, N);
  }
}

// Round 10
// 815.806 us; speedup vs baseline: 1.2196x; 1.2196x over previous
//
#include <hip/hip_runtime.h>
#include <hip/hip_bf16.h>

// ---------------------------------------------------------------------------
// WeightOnlyLinear: y = x @ dequant4(qweight, scales, qzeros) + bias
//   x (8192,4096) fp32 | scales (32,12288) | bias (12288) | qweight (512,12288)
//   qzeros (32,1536) | out (8192,12288) fp32
// R10: R9 GEMM (32x32x16 MFMA, ring-4 K-half slots, fragment-major LDS,
//      x4-unrolled phases, vmcnt(8)+1bar) with PRE-TILED OPERANDS IN DRAM:
//      prepasses write A'/B' in fragment-major tile layout, so GEMM staging
//      is one contiguous 1KB per wave (fully coalesced) AND ds_reads are
//      conflict-free with zero address math. Fixes R9's stage-scatter.
// Tile layout: tile (rb256, h) = 16KB: chunk c (16B), c = rb*128 + kh*64 +
//   kq2*32 + lr  ->  row = rb*32+lr, k = h*32 + kh*16 + kq2*8 (8 bf16).
// ---------------------------------------------------------------------------

typedef __attribute__((ext_vector_type(8))) short short8;
typedef __attribute__((ext_vector_type(4))) float f32x4;
typedef __attribute__((ext_vector_type(16))) float f32x16;

__device__ __forceinline__ short f2bf(float f) {
  unsigned u = __float_as_uint(f);
  u += 0x7fffu + ((u >> 16) & 1u);
  return (short)(u >> 16);
}

__device__ __forceinline__ void gload_lds16(const void* g, void* l) {
  __builtin_amdgcn_global_load_lds(
      (const __attribute__((address_space(1))) void*)g,
      (__attribute__((address_space(3))) void*)l,
      16, 0, 0);
}

__device__ __forceinline__ void bar() {
  asm volatile("" ::: "memory");
  __builtin_amdgcn_s_barrier();
  asm volatile("" ::: "memory");
}
__device__ __forceinline__ void wait_vm8() {
  asm volatile("s_waitcnt vmcnt(8)" ::: "memory");
}
__device__ __forceinline__ void wait_vm4() {
  asm volatile("s_waitcnt vmcnt(4)" ::: "memory");
}
__device__ __forceinline__ void wait_vm0() {
  asm volatile("s_waitcnt vmcnt(0)" ::: "memory");
}

// ---------------------------------------------------------------------------
// Pass 1 (R10): dequant qweight -> B' fragment-major tiles.
// Block = one (256-col, 32-k) tile; qweight word (k/8, n) == one chunk.
// Reads coalesced (word-rows), writes 512B segments.
// grid.x = (N/256)*(K/32), ordered (nb, h).
// ---------------------------------------------------------------------------
__global__ __launch_bounds__(256) void dequant_tile_kernel(
    const int* __restrict__ qweight, const int* __restrict__ qzeros,
    const float* __restrict__ scales, short* __restrict__ Bt,
    int N, int K) {
  const int kt = K >> 5;
  const int bx = blockIdx.x;
  const int nb = bx / kt, h = bx - nb * kt;
  const int t = threadIdx.x;
  const int n = nb * 256 + t;
  const int g = h >> 2;  // group = (h*32)/128
  const float sc = scales[(size_t)g * N + n];
  const int zw = qzeros[(size_t)g * (N >> 3) + (n >> 3)];
  const float zs = -(float)(((zw >> ((n & 7) * 4)) & 15) + 1) * sc;
  char* dst = (char*)Bt + (size_t)bx * 16384;
#pragma unroll
  for (int kw = 0; kw < 4; ++kw) {
    const int w = qweight[(size_t)(h * 4 + kw) * N + n];
    short8 v;
#pragma unroll
    for (int e = 0; e < 8; ++e)
      v[e] = f2bf(fmaf((float)((w >> (4 * e)) & 15), sc, zs));
    const int c = ((t >> 5) << 7) + ((kw >> 1) << 6) + ((kw & 1) << 5) + (t & 31);
    *(short8*)(dst + c * 16) = v;
  }
}

// ---------------------------------------------------------------------------
// Pass 2 (R10): x fp32 -> A' fragment-major tiles.
// Block = one (256-row, 32-k) tile; reads 128B row segments, writes 256B segs.
// grid.x = (M/256)*(K/32), ordered (mb, h).
// ---------------------------------------------------------------------------
__global__ __launch_bounds__(256) void cvt_tile_kernel(
    const float* __restrict__ x, short* __restrict__ xb, int K) {
  const int kt = K >> 5;
  const int bx = blockIdx.x;
  const int mb = bx / kt, h = bx - mb * kt;
  const float* xs = x + (size_t)mb * 256 * K + h * 32;
  char* dst = (char*)xb + (size_t)bx * 16384;
#pragma unroll
  for (int p = 0; p < 4; ++p) {
    const int t2 = p * 256 + threadIdx.x;
    const int row = t2 >> 2, kq = t2 & 3;
    const float* s = xs + (size_t)row * K + kq * 8;
    float4 f0 = *(const float4*)s;
    float4 f1 = *(const float4*)(s + 4);
    short8 v;
    v[0] = f2bf(f0.x); v[1] = f2bf(f0.y); v[2] = f2bf(f0.z); v[3] = f2bf(f0.w);
    v[4] = f2bf(f1.x); v[5] = f2bf(f1.y); v[6] = f2bf(f1.z); v[7] = f2bf(f1.w);
    const int c = ((row >> 5) << 7) + ((kq >> 1) << 6) + ((kq & 1) << 5) + (row & 31);
    *(short8*)(dst + c * 16) = v;
  }
}

// ---------------------------------------------------------------------------
// Pass 3 (R10): 256x256 GEMM, 512 threads = 8 waves (2M x 4N), wave 128x64.
// MFMA 32x32x16 bf16; wave tile 4x2 frags of 32x32.
// LDS ring: 4 slots x 32KB, fragment-major (A 16KB @0, B 16KB @16384).
// Staging: 4x gload_lds of contiguous 16B chunks -- wave reads 1KB linear
// from the pre-tiled A'/B'. Ledger: vmcnt(8)+bar per phase; tail 8/8/4/0.
// ---------------------------------------------------------------------------
#define GBM 256
#define GBN 256

__global__ __launch_bounds__(512, 2) void gemm256_kernel(
    const short* __restrict__ At, const short* __restrict__ Bt,
    const float* __restrict__ bias, float* __restrict__ C,
    int M, int N, int K) {
  __shared__ __align__(16) char lds[4][32768];
  const int tid = threadIdx.x;
  const int nbx = N / GBN;
  const int nwg = gridDim.x;
  int bid = blockIdx.x;
  if ((nwg & 7) == 0) bid = (bid & 7) * (nwg >> 3) + (bid >> 3);  // T1
  const int mb = bid / nbx;
  const int nb = bid % nbx;
  const int bm = mb * GBM, bn = nb * GBN;

  const int wid = tid >> 6, lane = tid & 63;
  const int wr = wid >> 2, wc = wid & 3;  // 2x4 wave grid
  const int l31 = lane & 31;
  const int lq2 = lane >> 5;

  const int P = K >> 5;  // K-halves; P % 4 == 0, P >= 8 (K % 256 == 0)

  char* lb = &lds[0][0];

  // ds_read base pointers [hi = slot>>1]; (slot&1)*32768 + i*2048 + kh*1024
  // are immediates.
  const char* aB[2];
  const char* bB[2];
  aB[0] = lb + wr * 8192 + lane * 16;          // rb = wr*4 + i
  aB[1] = aB[0] + 65536;
  bB[0] = lb + 16384 + wc * 4096 + lane * 16;  // cb = wc*2 + j
  bB[1] = bB[0] + 65536;

  // staging: pre-tiled sources, contiguous per K-half (16KB each)
  const char* gA = (const char*)At + (size_t)mb * P * 16384;
  const char* gB = (const char*)Bt + (size_t)nb * P * 16384;
  char* dstA0 = lb + tid * 16;
  char* dstA1 = dstA0 + 8192;
  char* dstB0 = dstA0 + 16384;
  char* dstB1 = dstA0 + 24576;
  const size_t t16 = (size_t)tid * 16;

#define STAGE(NSL, ASRC, BSRC)                          \
  do {                                                  \
    gload_lds16((ASRC) + t16, dstA0 + (NSL) * 32768);   \
    gload_lds16((ASRC) + t16 + 8192, dstA1 + (NSL) * 32768); \
    gload_lds16((BSRC) + t16, dstB0 + (NSL) * 32768);   \
    gload_lds16((BSRC) + t16 + 8192, dstB1 + (NSL) * 32768); \
  } while (0)

  f32x16 acc[4][2] = {};

#define PHASE(SL, ST)                                                         \
  do {                                                                        \
    short8 a0[4], a1[4], b0[2], b1[2];                                        \
    _Pragma("unroll") for (int i = 0; i < 4; ++i) a0[i] =                     \
        *(const short8*)(aB[(SL) >> 1] + ((SL)&1) * 32768 + i * 2048);        \
    _Pragma("unroll") for (int j = 0; j < 2; ++j) b0[j] =                     \
        *(const short8*)(bB[(SL) >> 1] + ((SL)&1) * 32768 + j * 2048);        \
    _Pragma("unroll") for (int i = 0; i < 4; ++i) a1[i] =                     \
        *(const short8*)(aB[(SL) >> 1] + ((SL)&1) * 32768 + i * 2048 + 1024); \
    _Pragma("unroll") for (int j = 0; j < 2; ++j) b1[j] =                     \
        *(const short8*)(bB[(SL) >> 1] + ((SL)&1) * 32768 + j * 2048 + 1024); \
    if (ST) STAGE(((SL) + 3) & 3, pA + (SL)*16384, pB + (SL)*16384);          \
    __builtin_amdgcn_s_setprio(1);                                            \
    _Pragma("unroll") for (int i = 0; i < 4; ++i)                             \
        _Pragma("unroll") for (int j = 0; j < 2; ++j) acc[i][j] =             \
            __builtin_amdgcn_mfma_f32_32x32x16_bf16(a0[i], b0[j], acc[i][j],  \
                                                    0, 0, 0);                 \
    _Pragma("unroll") for (int i = 0; i < 4; ++i)                             \
        _Pragma("unroll") for (int j = 0; j < 2; ++j) acc[i][j] =             \
            __builtin_amdgcn_mfma_f32_32x32x16_bf16(a1[i], b1[j], acc[i][j],  \
                                                    0, 0, 0);                 \
    __builtin_amdgcn_s_setprio(0);                                            \
  } while (0)

  // prologue: stage K-halves 0,1,2 into slots 0,1,2 (12 loads)
  STAGE(0, gA, gB);
  STAGE(1, gA + 16384, gB + 16384);
  STAGE(2, gA + 32768, gB + 32768);

  // main loop: PHASE(SL) stages K-half (4it+3+SL) from pA+SL*16384
  const char* pA = gA + 3 * 16384;
  const char* pB = gB + 3 * 16384;
  const int nIt = P / 4 - 1;
  for (int it = 0; it < nIt; ++it) {
    wait_vm8(); bar(); PHASE(0, true);
    wait_vm8(); bar(); PHASE(1, true);
    wait_vm8(); bar(); PHASE(2, true);
    wait_vm8(); bar(); PHASE(3, true);
    pA += 65536; pB += 65536;
  }
  // tail: phase P-4 stages K-half P-1; drain 8/8/4/0
  wait_vm8(); bar(); PHASE(0, true);
  wait_vm8(); bar(); PHASE(1, false);
  wait_vm4(); bar(); PHASE(2, false);
  wait_vm0(); bar(); PHASE(3, false);

#undef PHASE
#undef STAGE

  // epilogue: C = acc + bias.
  // 32x32 C/D map: col = lane&31, row = (reg&3) + 8*(reg>>2) + 4*(lane>>5)
  const int crow0 = bm + wr * 128 + 4 * lq2;
#pragma unroll
  for (int j = 0; j < 2; ++j) {
    const int ccol = bn + wc * 64 + j * 32 + l31;
    const float bv = bias[ccol];
#pragma unroll
    for (int i = 0; i < 4; ++i) {
#pragma unroll
      for (int reg = 0; reg < 16; ++reg) {
        const int row = crow0 + i * 32 + (reg & 3) + 8 * (reg >> 2);
        C[(size_t)row * N + ccol] = acc[i][j][reg] + bv;
      }
    }
  }
}

// ---------------------------------------------------------------------------
// Fallback prepasses (linear layouts) for non-256-divisible shapes.
// ---------------------------------------------------------------------------
__global__ __launch_bounds__(256) void dequant_kernel(
    const int* __restrict__ qweight, const int* __restrict__ qzeros,
    const float* __restrict__ scales, short* __restrict__ Wt,
    int in_f, int out_f) {
  __shared__ __align__(16) short T[64][72];
  const int n0 = blockIdx.x * 64;
  const int k0 = blockIdx.y * 64;
  const int t = threadIdx.x;
  const int nl = t & 63;
  const int kw = t >> 6;
  const int n = n0 + nl;
  const int g = k0 >> 7;
  const float sc = scales[(size_t)g * out_f + n];
  const int zpw = qzeros[(size_t)g * (out_f >> 3) + (n >> 3)];
  const float zp = (float)(((zpw >> ((n & 7) * 4)) & 15) + 1);
  const float zs = zp * sc;
#pragma unroll
  for (int rr = 0; rr < 2; ++rr) {
    const int kwi = kw + rr * 4;
    const int w = qweight[(size_t)((k0 >> 3) + kwi) * out_f + n];
    short8 v;
#pragma unroll
    for (int e = 0; e < 8; ++e) {
      float f = (float)((w >> (4 * e)) & 15) * sc - zs;
      v[e] = f2bf(f);
    }
    *(short8*)&T[nl][kwi * 8] = v;
  }
  __syncthreads();
#pragma unroll
  for (int rr = 0; rr < 2; ++rr) {
    const int c = rr * 256 + t;
    const int row = c >> 3, ch = c & 7;
    *(short8*)&Wt[(size_t)(n0 + row) * in_f + k0 + ch * 8] =
        *(const short8*)&T[row][ch * 8];
  }
}

__global__ __launch_bounds__(256) void cvt_kernel(
    const float* __restrict__ x, short* __restrict__ xb, long n8) {
  long i = (long)blockIdx.x * blockDim.x + threadIdx.x;
  if (i >= n8) return;
  const float* src = x + i * 8;
  float4 a = *(const float4*)src;
  float4 b = *(const float4*)(src + 4);
  short8 v;
  v[0] = f2bf(a.x); v[1] = f2bf(a.y); v[2] = f2bf(a.z); v[3] = f2bf(a.w);
  v[4] = f2bf(b.x); v[5] = f2bf(b.y); v[6] = f2bf(b.z); v[7] = f2bf(b.w);
  *(short8*)(xb + i * 8) = v;
}

// ---------------------------------------------------------------------------
// 128x128x64 GEMM (fallback for non-256-divisible shapes).
// ---------------------------------------------------------------------------
#define BM 128
#define BN 128
#define BK 64

template <bool A_BF16>
__global__ __launch_bounds__(256) void gemm_bias_kernel(
    const void* __restrict__ Av, const short* __restrict__ Bt,
    const float* __restrict__ bias, float* __restrict__ C,
    int M, int N, int K) {
  __shared__ __align__(16) short As[BM * BK];
  __shared__ __align__(16) short Bs[BN * BK];
  const int tid = threadIdx.x;
  const int bm = blockIdx.y * BM;
  const int bn = blockIdx.x * BN;
  const int wid = tid >> 6, lane = tid & 63;
  const int wr = wid >> 1, wc = wid & 1;
  const int lrow = lane & 15;
  const int lk = (lane >> 4) * 8;

  f32x4 acc[4][4] = {};

  for (int kt = 0; kt < K; kt += BK) {
    if constexpr (A_BF16) {
      const short* A = (const short*)Av;
#pragma unroll
      for (int r = 0; r < 4; ++r) {
        const int c = r * 256 + tid;
        const int row = c >> 3, ch = c & 7;
        gload_lds16(A + (size_t)(bm + row) * K + kt + ch * 8,
                    (char*)As + c * 16);
      }
    } else {
      const float* A = (const float*)Av;
#pragma unroll
      for (int r = 0; r < 4; ++r) {
        const int c = r * 256 + tid;
        const int row = c >> 3, ch = c & 7;
        const float* src = A + (size_t)(bm + row) * K + kt + ch * 8;
        float4 f0 = *(const float4*)src;
        float4 f1 = *(const float4*)(src + 4);
        short8 v;
        v[0] = f2bf(f0.x); v[1] = f2bf(f0.y); v[2] = f2bf(f0.z); v[3] = f2bf(f0.w);
        v[4] = f2bf(f1.x); v[5] = f2bf(f1.y); v[6] = f2bf(f1.z); v[7] = f2bf(f1.w);
        *(short8*)((char*)As + c * 16) = v;
      }
    }
#pragma unroll
    for (int r = 0; r < 4; ++r) {
      const int c = r * 256 + tid;
      const int row = c >> 3, ch = c & 7;
      gload_lds16(Bt + (size_t)(bn + row) * K + kt + ch * 8,
                  (char*)Bs + c * 16);
    }
    __syncthreads();
#pragma unroll
    for (int kk = 0; kk < 2; ++kk) {
      short8 af[4], bf[4];
#pragma unroll
      for (int i = 0; i < 4; ++i)
        af[i] = *(const short8*)&As[(wr * 64 + i * 16 + lrow) * BK + kk * 32 + lk];
#pragma unroll
      for (int j = 0; j < 4; ++j)
        bf[j] = *(const short8*)&Bs[(wc * 64 + j * 16 + lrow) * BK + kk * 32 + lk];
#pragma unroll
      for (int i = 0; i < 4; ++i)
#pragma unroll
        for (int j = 0; j < 4; ++j)
          acc[i][j] = __builtin_amdgcn_mfma_f32_16x16x32_bf16(
              af[i], bf[j], acc[i][j], 0, 0, 0);
    }
    __syncthreads();
  }

  const int crow0 = bm + wr * 64 + (lane >> 4) * 4;
  const int ccol0 = bn + wc * 64 + (lane & 15);
#pragma unroll
  for (int j = 0; j < 4; ++j) {
    const float bv = bias[ccol0 + j * 16];
#pragma unroll
    for (int i = 0; i < 4; ++i) {
#pragma unroll
      for (int r = 0; r < 4; ++r) {
        C[(size_t)(crow0 + i * 16 + r) * N + ccol0 + j * 16] = acc[i][j][r] + bv;
      }
    }
  }
}

// ---------------------------------------------------------------------------
// Last-resort fallback: naive fused dequant GEMM.
// ---------------------------------------------------------------------------
__global__ __launch_bounds__(256) void naive_kernel(
    const float* __restrict__ x, const float* __restrict__ scales,
    const float* __restrict__ bias, const int* __restrict__ qw,
    const int* __restrict__ qz, float* __restrict__ out,
    int M, int K, int N) {
  long idx = (long)blockIdx.x * blockDim.x + threadIdx.x;
  if (idx >= (long)M * N) return;
  const int n = (int)(idx % N);
  const int m = (int)(idx / N);
  float acc = 0.f;
  for (int g = 0; g < K / 128; ++g) {
    const float sc = scales[(size_t)g * N + n];
    const float zp =
        (float)(((qz[(size_t)g * (N >> 3) + (n >> 3)] >> ((n & 7) * 4)) & 15) + 1);
    const float zs = zp * sc;
    for (int kw = 0; kw < 16; ++kw) {
      const int w = qw[(size_t)(g * 16 + kw) * N + n];
      const float* xp = &x[(size_t)m * K + g * 128 + kw * 8];
#pragma unroll
      for (int e = 0; e < 8; ++e)
        acc += xp[e] * ((float)((w >> (4 * e)) & 15) * sc - zs);
    }
  }
  out[idx] = acc + bias[n];
}

// ---------------------------------------------------------------------------
extern "C" void kernel_launch(void* const* d_in, const int* in_sizes, int n_in,
                              void* d_out, int out_size, void* d_ws,
                              size_t ws_size, hipStream_t stream) {
  const float* x = (const float*)d_in[0];
  const float* scales = (const float*)d_in[1];
  const float* bias = (const float*)d_in[2];
  const int* qweight = (const int*)d_in[3];
  const int* qzeros = (const int*)d_in[4];
  float* out = (float*)d_out;

  const int out_f = in_sizes[2];            // 12288
  const int kwords = in_sizes[3] / out_f;   // 512
  const int in_f = kwords * 8;              // 4096
  const int tokens = in_sizes[0] / in_f;    // 8192
  const int M = tokens, K = in_f, N = out_f;

  const size_t wt_bytes = (size_t)K * N * sizeof(short);
  const size_t xb_bytes = (size_t)M * K * sizeof(short);

  const bool div128 = (M % BM == 0) && (N % BN == 0) && (K % BK == 0) &&
                      (K % 128 == 0) && (N % 64 == 0);
  const bool div256 = (M % GBM == 0) && (N % GBN == 0) && (K % 256 == 0);

  if (div256 && ws_size >= wt_bytes + xb_bytes) {
    // R10 pre-tiled path
    short* Bt = (short*)d_ws;                           // B' fragment tiles
    short* At = (short*)((char*)d_ws + wt_bytes);       // A' fragment tiles
    const int kt = K >> 5;
    dequant_tile_kernel<<<(N / 256) * kt, 256, 0, stream>>>(
        qweight, qzeros, scales, Bt, N, K);
    cvt_tile_kernel<<<(M / 256) * kt, 256, 0, stream>>>(x, At, K);
    gemm256_kernel<<<(M / GBM) * (N / GBN), 512, 0, stream>>>(
        At, Bt, bias, out, M, N, K);
  } else if (div128 && ws_size >= wt_bytes + xb_bytes) {
    short* Wt = (short*)d_ws;
    short* xb = (short*)((char*)d_ws + wt_bytes);
    dequant_kernel<<<dim3(N / 64, K / 64), 256, 0, stream>>>(
        qweight, qzeros, scales, Wt, K, N);
    const long n8 = (long)M * K / 8;
    cvt_kernel<<<(int)((n8 + 255) / 256), 256, 0, stream>>>(x, xb, n8);
    gemm_bias_kernel<true><<<dim3(N / BN, M / BM), 256, 0, stream>>>(
        xb, Wt, bias, out, M, N, K);
  } else if (div128 && ws_size >= wt_bytes) {
    short* Wt = (short*)d_ws;
    dequant_kernel<<<dim3(N / 64, K / 64), 256, 0, stream>>>(
        qweight, qzeros, scales, Wt, K, N);
    gemm_bias_kernel<false><<<dim3(N / BN, M / BM), 256, 0, stream>>>(
        x, Wt, bias, out, M, N, K);
  } else {
    const long total = (long)M * N;
    naive_kernel<<<(int)((total + 255) / 256), 256, 0, stream>>>(
        x, scales, bias, qweight, qzeros, out, M, K, N);
  }
}